// Round 1
// baseline (635.300 us; speedup 1.0000x reference)
//
#include <hip/hip_runtime.h>

typedef __bf16 bf16;
typedef bf16 bf16x4 __attribute__((ext_vector_type(4)));
typedef bf16 bf16x8 __attribute__((ext_vector_type(8)));
typedef float f32x4 __attribute__((ext_vector_type(4)));

#define MFMA16(a, b, c) __builtin_amdgcn_mfma_f32_16x16x32_bf16((a), (b), (c), 0, 0, 0)

// ---------------- geometry ----------------
// windows B_=8192 (= 8 imgs * 1024), N=49 tokens, C=128, H=4 heads, hd=32
// LDS layout (bytes), total exactly 65536 -> 2 blocks/CU:
//   xs   @ 0      : [49][136] bf16 = 13328   (x tile, padded stride 136)
//   qf   @ 13328  : [4][4][64][8] bf16 = 16384  (Q in A-frag order, scale folded)
//   paf  @ 0      : [4][4][2][64][8] bf16 = 32768 (P in A-frag order; OVERLAYS xs+qf)
//   kf   @ 32768  : [4][4][64][8] bf16 = 16384  (K in B-frag order)
//   vtf  @ 49152  : [4][2][2][64][8] bf16 = 16384 (V^T in B-frag order, K-pad zeroed)
//   ao   @ 32768  : [49][136] bf16 = 13328  (attn out; OVERLAYS kf)
#define XS_OFF 0
#define QF_OFF 13328
#define PAF_OFF 0
#define KF_OFF 32768
#define VTF_OFF 49152
#define AO_OFF 32768
#define SMEM_BYTES 65536

__global__ void prep_kernel(const float* __restrict__ qkv_w, const float* __restrict__ proj_w,
                            const float* __restrict__ rpb, const int* __restrict__ rel,
                            bf16* __restrict__ wq, bf16* __restrict__ wp,
                            float* __restrict__ biasg) {
  int i = blockIdx.x * 256 + threadIdx.x;
  if (i < 49152) {
    wq[i] = (bf16)qkv_w[i];
  } else if (i < 65536) {
    wp[i - 49152] = (bf16)proj_w[i - 49152];
  } else if (i < 75140) {
    int t = i - 65536;            // t = h*2401 + (n*49+m)
    int nm = t % 2401, h = t / 2401;
    biasg[t] = rpb[rel[nm] * 4 + h];
  }
}

__global__ void __launch_bounds__(256, 2)
swin_kernel(const float* __restrict__ x, const float* __restrict__ qkv_b,
            const float* __restrict__ proj_b, const float* __restrict__ maskp,
            const bf16* __restrict__ wq, const bf16* __restrict__ wp,
            const float* __restrict__ biasg, float* __restrict__ outp) {
  __shared__ __align__(16) unsigned char smem[SMEM_BYTES];
  bf16* xsL  = (bf16*)(smem + XS_OFF);
  bf16* qfL  = (bf16*)(smem + QF_OFF);
  bf16* pafL = (bf16*)(smem + PAF_OFF);
  bf16* kfL  = (bf16*)(smem + KF_OFF);
  bf16* vtfL = (bf16*)(smem + VTF_OFF);
  bf16* aoL  = (bf16*)(smem + AO_OFF);

  const int tid = threadIdx.x;
  // swizzle so 8 consecutive blocks share one window mask (x8 L2 reuse on mask)
  const int bi = blockIdx.x;
  const int img = bi & 7;
  const int widx = bi >> 3;            // 0..1023
  const int b = img * 1024 + widx;     // window index into x / out
  const int w = tid >> 6;              // wave id 0..3 (= head in attention phases)
  const int l = tid & 63;
  const int lane16 = l & 15;
  const int grp = l >> 4;              // 0..3
  const float scale = 0.17677669529663687f;  // 32^-0.5

  // ---------------- P0: stage x -> bf16 LDS; zero V^T K-pad ----------------
  {
    const float4* xb = (const float4*)(x + (size_t)b * 6272);
#pragma unroll
    for (int it = 0; it < 7; ++it) {
      int i = tid + it * 256;
      if (i < 1568) {                  // 1568*4 = 6272 = 49*128 exactly
        float4 v = xb[i];
        int e = i << 2, row = e >> 7, col = e & 127;
        bf16x4 bv;
        bv[0] = (bf16)v.x; bv[1] = (bf16)v.y; bv[2] = (bf16)v.z; bv[3] = (bf16)v.w;
        *(bf16x4*)(xsL + row * 136 + col) = bv;
      }
    }
    // zero vtf slots for m=48..63 (K-dim pad of PV). regions: (h*2+dt)=tid>>5, kb=1
    int region = tid >> 5;
    int off = (tid & 31) * 8;
    bf16x8 zz;
#pragma unroll
    for (int q = 0; q < 8; ++q) zz[q] = (bf16)0.f;
    *(bf16x8*)(vtfL + (region * 2 + 1) * 512 + 256 + off) = zz;
  }
  __syncthreads();

  // ---------------- P1: QKV GEMM  (qkv[n][j] = sum_c x[n][c] * Wq[j][c] + b[j]) ----
  {
    bf16x8 ax[4][4];
#pragma unroll
    for (int nt = 0; nt < 4; ++nt) {
      int rw = nt * 16 + lane16; if (rw > 48) rw = 48;   // clamp pad rows
#pragma unroll
      for (int kb = 0; kb < 4; ++kb)
        ax[nt][kb] = *(const bf16x8*)(xsL + rw * 136 + kb * 32 + grp * 8);
    }
#pragma unroll
    for (int jj = 0; jj < 6; ++jj) {
      const int jb = w * 6 + jj;                 // 0..23
      const int j = jb * 16 + lane16;            // output channel
      bf16x8 bw[4];
#pragma unroll
      for (int kb = 0; kb < 4; ++kb)
        bw[kb] = *(const bf16x8*)(wq + j * 128 + kb * 32 + grp * 8);
      const float bj = qkv_b[j];
      const int part = jb >> 3;                  // 0=q 1=k 2=v (wave-uniform)
      const int h = (jb >> 1) & 3;               // head (uniform)
      const int d0 = (jb & 1) * 16;
#pragma unroll
      for (int nt = 0; nt < 4; ++nt) {
        f32x4 acc = {0.f, 0.f, 0.f, 0.f};
#pragma unroll
        for (int kb = 0; kb < 4; ++kb) acc = MFMA16(ax[nt][kb], bw[kb], acc);
#pragma unroll
        for (int r = 0; r < 4; ++r) {
          const int nrow = nt * 16 + grp * 4 + r;
          if (nrow < 49) {
            float v = acc[r] + bj;
            const int d = d0 + lane16;
            if (part == 0) {
              v *= scale;
              qfL[(((h * 4 + nt) * 64) + (grp * 4 + r) + ((d >> 3) << 4)) * 8 + (d & 7)] = (bf16)v;
            } else if (part == 1) {
              kfL[(((h * 4 + nt) * 64) + (grp * 4 + r) + ((d >> 3) << 4)) * 8 + (d & 7)] = (bf16)v;
            } else {
              const int dt = d >> 4, kb2 = nrow >> 5;
              const int lp = (d & 15) + (((nrow >> 3) & 3) << 4);
              vtfL[((((h * 2 + dt) * 2 + kb2) * 64) + lp) * 8 + (nrow & 7)] = (bf16)v;
            }
          }
        }
      }
    }
  }
  __syncthreads();

  // ---------------- P2a: S = (q*scale) @ k^T  (wave w = head w) ----------------
  const int h = w;
  f32x4 S[4][4];
  {
    bf16x8 qa[4], ka[4];
#pragma unroll
    for (int t = 0; t < 4; ++t) {
      qa[t] = *(const bf16x8*)(qfL + ((h * 4 + t) * 64 + l) * 8);
      ka[t] = *(const bf16x8*)(kfL + ((h * 4 + t) * 64 + l) * 8);
    }
#pragma unroll
    for (int nt = 0; nt < 4; ++nt)
#pragma unroll
      for (int mt = 0; mt < 4; ++mt) {
        f32x4 zz = {0.f, 0.f, 0.f, 0.f};
        S[nt][mt] = MFMA16(qa[nt], ka[mt], zz);
      }
  }
  __syncthreads();   // all qf reads done before paf overlays it

  // ---------------- P2b: bias+mask, softmax (rows in 16-lane groups), write P ----
  float rinv[4][4];
  {
    const float* biash = biasg + h * 2401;
    const float* maskw = maskp + (size_t)widx * 2401;
#pragma unroll
    for (int nt = 0; nt < 4; ++nt) {
#pragma unroll
      for (int mt = 0; mt < 4; ++mt) {
        const int m = mt * 16 + lane16;
#pragma unroll
        for (int r = 0; r < 4; ++r) {
          const int n = nt * 16 + grp * 4 + r;
          float s = S[nt][mt][r];
          if (m < 49) {
            if (n < 49) s += biash[n * 49 + m] + maskw[n * 49 + m];
          } else {
            s = -1e30f;
          }
          S[nt][mt][r] = s;
        }
      }
#pragma unroll
      for (int r = 0; r < 4; ++r) {
        float mx = fmaxf(fmaxf(S[nt][0][r], S[nt][1][r]), fmaxf(S[nt][2][r], S[nt][3][r]));
        mx = fmaxf(mx, __shfl_xor(mx, 1));
        mx = fmaxf(mx, __shfl_xor(mx, 2));
        mx = fmaxf(mx, __shfl_xor(mx, 4));
        mx = fmaxf(mx, __shfl_xor(mx, 8));
        float sum = 0.f;
#pragma unroll
        for (int mt = 0; mt < 4; ++mt) {
          float p = __expf(S[nt][mt][r] - mx);
          S[nt][mt][r] = p;
          sum += p;
        }
        sum += __shfl_xor(sum, 1);
        sum += __shfl_xor(sum, 2);
        sum += __shfl_xor(sum, 4);
        sum += __shfl_xor(sum, 8);
        rinv[nt][r] = 1.f / sum;    // normalization deferred to PV epilogue
      }
      // write P (unnormalized) into A-frag order, zero K-pad m>=49
#pragma unroll
      for (int mt = 0; mt < 4; ++mt) {
        const int m = mt * 16 + lane16;
        const int kb2 = m >> 5;
        const int lpb = (grp * 4) + (((m >> 3) & 3) << 4);
#pragma unroll
        for (int r = 0; r < 4; ++r) {
          float p = (m < 49) ? S[nt][mt][r] : 0.f;
          pafL[((((w * 4 + nt) * 2 + kb2) * 64) + lpb + r) * 8 + (m & 7)] = (bf16)p;
        }
      }
    }
  }

  // ---------------- P3: O = P @ V, normalize, write attn-out ----------------
  {
    bf16x8 vb2[2][2], pa[4][2];
#pragma unroll
    for (int dt = 0; dt < 2; ++dt)
#pragma unroll
      for (int kb = 0; kb < 2; ++kb)
        vb2[dt][kb] = *(const bf16x8*)(vtfL + (((h * 2 + dt) * 2 + kb) * 64 + l) * 8);
#pragma unroll
    for (int nt = 0; nt < 4; ++nt)
#pragma unroll
      for (int kb = 0; kb < 2; ++kb)
        pa[nt][kb] = *(const bf16x8*)(pafL + (((w * 4 + nt) * 2 + kb) * 64 + l) * 8);
    f32x4 O[4][2];
#pragma unroll
    for (int nt = 0; nt < 4; ++nt)
#pragma unroll
      for (int dt = 0; dt < 2; ++dt) {
        f32x4 acc = {0.f, 0.f, 0.f, 0.f};
        acc = MFMA16(pa[nt][0], vb2[dt][0], acc);
        acc = MFMA16(pa[nt][1], vb2[dt][1], acc);
        O[nt][dt] = acc;
      }
    __syncthreads();   // kf reads long done; ao overlays kf; ensure no wave lags in P2a/P3 reads
#pragma unroll
    for (int nt = 0; nt < 4; ++nt)
#pragma unroll
      for (int r = 0; r < 4; ++r) {
        const int n = nt * 16 + grp * 4 + r;
        if (n < 49) {
          const float ri = rinv[nt][r];
#pragma unroll
          for (int dt = 0; dt < 2; ++dt) {
            const int c = h * 32 + dt * 16 + lane16;
            aoL[n * 136 + c] = (bf16)(O[nt][dt][r] * ri);
          }
        }
      }
  }
  __syncthreads();

  // ---------------- P4: out = ao @ proj_w^T + proj_b ----------------
  {
    bf16x8 aa[4][4];
#pragma unroll
    for (int nt = 0; nt < 4; ++nt) {
      int rw = nt * 16 + lane16; if (rw > 48) rw = 48;
#pragma unroll
      for (int kb = 0; kb < 4; ++kb)
        aa[nt][kb] = *(const bf16x8*)(aoL + rw * 136 + kb * 32 + grp * 8);
    }
    float* outb = outp + (size_t)b * 6272;
#pragma unroll
    for (int ee = 0; ee < 2; ++ee) {
      const int eb = w * 2 + ee;
      const int e = eb * 16 + lane16;
      bf16x8 bw[4];
#pragma unroll
      for (int kb = 0; kb < 4; ++kb)
        bw[kb] = *(const bf16x8*)(wp + e * 128 + kb * 32 + grp * 8);
      const float be = proj_b[e];
#pragma unroll
      for (int nt = 0; nt < 4; ++nt) {
        f32x4 acc = {0.f, 0.f, 0.f, 0.f};
#pragma unroll
        for (int kb = 0; kb < 4; ++kb) acc = MFMA16(aa[nt][kb], bw[kb], acc);
#pragma unroll
        for (int r = 0; r < 4; ++r) {
          const int n = nt * 16 + grp * 4 + r;
          if (n < 49) outb[n * 128 + e] = acc[r] + be;
        }
      }
    }
  }
}

extern "C" void kernel_launch(void* const* d_in, const int* in_sizes, int n_in,
                              void* d_out, int out_size, void* d_ws, size_t ws_size,
                              hipStream_t stream) {
  const float* x      = (const float*)d_in[0];
  const float* qkv_w  = (const float*)d_in[1];
  const float* qkv_b  = (const float*)d_in[2];
  const float* proj_w = (const float*)d_in[3];
  const float* proj_b = (const float*)d_in[4];
  const float* rpb    = (const float*)d_in[5];
  const float* maskp  = (const float*)d_in[6];
  const int*   rel    = (const int*)d_in[7];

  bf16* wq = (bf16*)d_ws;                         // 49152 bf16
  bf16* wp = wq + 49152;                          // 16384 bf16
  float* biasg = (float*)((char*)d_ws + 131072);  // 9604 f32: [4][49][49]

  prep_kernel<<<294, 256, 0, stream>>>(qkv_w, proj_w, rpb, rel, wq, wp, biasg);
  swin_kernel<<<8192, 256, 0, stream>>>(x, qkv_b, proj_b, maskp, wq, wp, biasg,
                                        (float*)d_out);
}

// Round 2
// 620.037 us; speedup vs baseline: 1.0246x; 1.0246x over previous
//
#include <hip/hip_runtime.h>

typedef __bf16 bf16;
typedef bf16 bf16x4 __attribute__((ext_vector_type(4)));
typedef bf16 bf16x8 __attribute__((ext_vector_type(8)));
typedef float f32x4 __attribute__((ext_vector_type(4)));

#define MFMA16(a, b, c) __builtin_amdgcn_mfma_f32_16x16x32_bf16((a), (b), (c), 0, 0, 0)

// ---------------- geometry ----------------
// B_=8192 windows (8 imgs x 1024), N=49 tokens (pad 64), C=128, H=4 heads, hd=32
// LDS layout (bytes), total 53248 -> 3 blocks/CU:
//   vt @ 0     : [128][72] bf16 = 18432   V^T natural [d][m], K-pad (m>=49) zeroed
//   q  @ 18432 : [64][136] bf16 = 17408   q natural [n][d], scale+bias folded
//   k  @ 35840 : [64][136] bf16 = 17408   k natural [n][d]   (ends 53248)
//   Pn @ 18432 : 4 x [49][72] bf16 = 28224  P natural [n][m] per head (over q,k after B2)
//   ao @ 18432 : [64][136] bf16 = 17408   attn-out natural [n][c] (over Pn after B3)
#define VT_OFF 0
#define Q_OFF 18432
#define K_OFF 35840
#define PN_OFF 18432
#define AO_OFF 18432
#define SMEM_BYTES 53248

__global__ void prep_kernel(const float* __restrict__ qkv_w, const float* __restrict__ proj_w,
                            const float* __restrict__ rpb, const int* __restrict__ rel,
                            const float* __restrict__ mask,
                            bf16* __restrict__ wq, bf16* __restrict__ wp,
                            float* __restrict__ biasp, bf16* __restrict__ maskb) {
  int i = blockIdx.x * 256 + threadIdx.x;
  if (i < 49152) { wq[i] = (bf16)qkv_w[i]; return; }
  i -= 49152;
  if (i < 16384) { wp[i] = (bf16)proj_w[i]; return; }
  i -= 16384;
  if (i < 16384) {   // biasp[h][n=64][m=64] f32, zero-padded
    int h = i >> 12, n = (i >> 6) & 63, m = i & 63;
    biasp[i] = (n < 49 && m < 49) ? rpb[rel[n * 49 + m] * 4 + h] : 0.f;
    return;
  }
  i -= 16384;
  if (i < 4194304) { // maskb[wi][n=64][m=64] bf16, zero-padded
    int wi = i >> 12, n = (i >> 6) & 63, m = i & 63;
    maskb[i] = (bf16)((n < 49 && m < 49) ? mask[wi * 2401 + n * 49 + m] : 0.f);
  }
}

__global__ void __launch_bounds__(256, 3)
swin_kernel(const float* __restrict__ x, const float* __restrict__ qkv_b,
            const float* __restrict__ proj_b, const bf16* __restrict__ wq,
            const bf16* __restrict__ wp, const float* __restrict__ biasp,
            const bf16* __restrict__ maskb, float* __restrict__ outp) {
  __shared__ __align__(16) unsigned char smem[SMEM_BYTES];
  bf16* vtL = (bf16*)(smem + VT_OFF);
  bf16* qL  = (bf16*)(smem + Q_OFF);
  bf16* kL  = (bf16*)(smem + K_OFF);
  bf16* pnL = (bf16*)(smem + PN_OFF);
  bf16* aoL = (bf16*)(smem + AO_OFF);

  const int tid = threadIdx.x;
  const int bi = blockIdx.x;
  const int img = bi & 7;                 // 8 consecutive blocks share one mask window
  const int widx = bi >> 3;               // 0..1023
  const int b = img * 1024 + widx;
  const int w = tid >> 6;                 // wave id (= head in attention phases)
  const int l = tid & 63;
  const int l16 = l & 15;
  const int grp = l >> 4;
  const float scale = 0.17677669529663687f;  // 32^-0.5

  // ---------- P1: QKV GEMM. x-fragments straight from global (L2-resident) ----------
  bf16x8 xf[4][4];
  {
    const float* xb = x + (size_t)b * 6272;
#pragma unroll
    for (int nt = 0; nt < 4; ++nt) {
      int n = nt * 16 + l16; if (n > 48) n = 48;   // clamp pad rows (stay in-window)
      const float* rp = xb + n * 128 + grp * 8;
#pragma unroll
      for (int kb = 0; kb < 4; ++kb) {
        float4 lo = *(const float4*)(rp + kb * 32);
        float4 hi = *(const float4*)(rp + kb * 32 + 4);
        bf16x8 r;
        r[0] = (bf16)lo.x; r[1] = (bf16)lo.y; r[2] = (bf16)lo.z; r[3] = (bf16)lo.w;
        r[4] = (bf16)hi.x; r[5] = (bf16)hi.y; r[6] = (bf16)hi.z; r[7] = (bf16)hi.w;
        xf[nt][kb] = r;
      }
    }
  }
#pragma unroll
  for (int jj = 0; jj < 6; ++jj) {
    const int jb = w * 6 + jj;            // 0..23 (0-7 q, 8-15 k, 16-23 v)
    bf16x8 wf[4];
    const bf16* wrow = wq + (jb * 16 + l16) * 128 + grp * 8;
#pragma unroll
    for (int kb = 0; kb < 4; ++kb) wf[kb] = *(const bf16x8*)(wrow + kb * 32);
    if (jb < 16) {
      // swapped GEMM: C[col=n][row=j] -> lane holds 4 consecutive j -> packed b64 row store
      float4 b4 = *(const float4*)(qkv_b + jb * 16 + (grp << 2));
      const int col = ((jb & 7) << 4) + (grp << 2);
      bf16* dst = (jb < 8) ? qL : kL;
      const float sc = (jb < 8) ? scale : 1.f;
#pragma unroll
      for (int nt = 0; nt < 4; ++nt) {
        f32x4 acc = {0.f, 0.f, 0.f, 0.f};
#pragma unroll
        for (int kb = 0; kb < 4; ++kb) acc = MFMA16(wf[kb], xf[nt][kb], acc);
        bf16x4 pv;
#pragma unroll
        for (int r = 0; r < 4; ++r) pv[r] = (bf16)((acc[r] + b4[r]) * sc);
        *(bf16x4*)(dst + (nt * 16 + l16) * 136 + col) = pv;
      }
    } else {
      // normal GEMM: C[col=d][row=n] -> lane holds 4 consecutive n -> packed V^T[d][m] store
      const float bj = qkv_b[jb * 16 + l16];
      const int d = ((jb - 16) << 4) + l16;
#pragma unroll
      for (int nt = 0; nt < 4; ++nt) {
        f32x4 acc = {0.f, 0.f, 0.f, 0.f};
#pragma unroll
        for (int kb = 0; kb < 4; ++kb) acc = MFMA16(xf[nt][kb], wf[kb], acc);
        const int n0 = nt * 16 + (grp << 2);
        bf16x4 pv;
#pragma unroll
        for (int r = 0; r < 4; ++r) {
          float v = acc[r] + bj;
          if (nt == 3) v = (n0 + r < 49) ? v : 0.f;   // zero K-pad for PV
          pv[r] = (bf16)v;
        }
        *(bf16x4*)(vtL + d * 72 + n0) = pv;
      }
    }
  }
  __syncthreads();  // B1: q,k,vt ready

  // ---------- P2a: S^T = K·Q^T (swapped) — wave w = head w ----------
  const int h = w;
  f32x4 S[4][4];  // [mt][nt]; C[col=n=nt*16+l16][row=m=mt*16+grp*4+r]
  {
    bf16x8 qa[4], ka[4];
#pragma unroll
    for (int t = 0; t < 4; ++t) {
      qa[t] = *(const bf16x8*)(qL + (t * 16 + l16) * 136 + h * 32 + grp * 8);
      ka[t] = *(const bf16x8*)(kL + (t * 16 + l16) * 136 + h * 32 + grp * 8);
    }
#pragma unroll
    for (int mt = 0; mt < 4; ++mt)
#pragma unroll
      for (int nt = 0; nt < 4; ++nt) {
        f32x4 z = {0.f, 0.f, 0.f, 0.f};
        S[mt][nt] = MFMA16(ka[mt], qa[nt], z);
      }
  }
  __syncthreads();  // B2: all q,k reads done (Pn overlays them)

  // ---------- P2b: bias+mask (vector loads), softmax over m, packed P store ----------
  {
    const float* bh = biasp + h * 4096;
    const bf16* mw = maskb + (size_t)widx * 4096;
#pragma unroll
    for (int nt = 0; nt < 4; ++nt) {
      const int n = nt * 16 + l16;
      const int rowo = n * 64 + (grp << 2);
      float p[4][4];
#pragma unroll
      for (int mt = 0; mt < 4; ++mt) {
        float4 b4 = *(const float4*)(bh + rowo + mt * 16);
        bf16x4 m4 = *(const bf16x4*)(mw + rowo + mt * 16);
#pragma unroll
        for (int r = 0; r < 4; ++r) {
          float s = S[mt][nt][r] + b4[r] + (float)m4[r];
          if (mt == 3) s = ((grp << 2) + r < 1) ? s : -1e30f;  // m=48 valid, 49..63 masked
          p[mt][r] = s;
        }
      }
      float mx = p[0][0];
#pragma unroll
      for (int mt = 0; mt < 4; ++mt)
#pragma unroll
        for (int r = 0; r < 4; ++r) mx = fmaxf(mx, p[mt][r]);
      mx = fmaxf(mx, __shfl_xor(mx, 16));
      mx = fmaxf(mx, __shfl_xor(mx, 32));
      float sum = 0.f;
#pragma unroll
      for (int mt = 0; mt < 4; ++mt)
#pragma unroll
        for (int r = 0; r < 4; ++r) { float e = __expf(p[mt][r] - mx); p[mt][r] = e; sum += e; }
      sum += __shfl_xor(sum, 16);
      sum += __shfl_xor(sum, 32);
      const float ri = 1.f / sum;
      if (n < 49) {
        bf16* pd = pnL + h * 3528 + n * 72 + (grp << 2);
#pragma unroll
        for (int mt = 0; mt < 4; ++mt) {
          bf16x4 pv;
#pragma unroll
          for (int r = 0; r < 4; ++r) pv[r] = (bf16)(p[mt][r] * ri);
          *(bf16x4*)(pd + mt * 16) = pv;
        }
      }
    }
  }
  // no barrier: wave reads only its own head's Pn (written by itself); vt ordered by B1

  // ---------- P3: O = P·V (normal), epilogue into ao after barrier ----------
  f32x4 O[4][2];
  {
    bf16x8 pa[4][2], vb[2][2];
#pragma unroll
    for (int nt = 0; nt < 4; ++nt)
#pragma unroll
      for (int kb = 0; kb < 2; ++kb)
        pa[nt][kb] = *(const bf16x8*)(pnL + h * 3528 + (nt * 16 + l16) * 72 + kb * 32 + grp * 8);
#pragma unroll
    for (int dt = 0; dt < 2; ++dt)
#pragma unroll
      for (int kb = 0; kb < 2; ++kb)
        vb[dt][kb] = *(const bf16x8*)(vtL + (h * 32 + dt * 16 + l16) * 72 + kb * 32 + grp * 8);
#pragma unroll
    for (int nt = 0; nt < 4; ++nt)
#pragma unroll
      for (int dt = 0; dt < 2; ++dt) {
        f32x4 acc = {0.f, 0.f, 0.f, 0.f};
        acc = MFMA16(pa[nt][0], vb[dt][0], acc);
        acc = MFMA16(pa[nt][1], vb[dt][1], acc);
        O[nt][dt] = acc;
      }
  }
  __syncthreads();  // B3: all Pn/vt reads done (ao overlays Pn)
#pragma unroll
  for (int nt = 0; nt < 4; ++nt)
#pragma unroll
    for (int dt = 0; dt < 2; ++dt) {
      const int c = h * 32 + dt * 16 + l16;
#pragma unroll
      for (int r = 0; r < 4; ++r) {
        const int n = nt * 16 + (grp << 2) + r;
        aoL[n * 136 + c] = (bf16)O[nt][dt][r];
      }
    }
  __syncthreads();  // B4: ao ready

  // ---------- P4: out = ao·Wp^T + b (swapped) -> coalesced f32x4 stores ----------
  {
    bf16x8 af[4][4];
#pragma unroll
    for (int nt = 0; nt < 4; ++nt)
#pragma unroll
      for (int kb = 0; kb < 4; ++kb)
        af[nt][kb] = *(const bf16x8*)(aoL + (nt * 16 + l16) * 136 + kb * 32 + grp * 8);
    float* ob = outp + (size_t)b * 6272;
#pragma unroll
    for (int ee = 0; ee < 2; ++ee) {
      const int eb = w * 2 + ee;
      bf16x8 wa[4];
      const bf16* wrow = wp + (eb * 16 + l16) * 128 + grp * 8;
#pragma unroll
      for (int kb = 0; kb < 4; ++kb) wa[kb] = *(const bf16x8*)(wrow + kb * 32);
      float4 pb4 = *(const float4*)(proj_b + eb * 16 + (grp << 2));
#pragma unroll
      for (int nt = 0; nt < 4; ++nt) {
        f32x4 acc = {0.f, 0.f, 0.f, 0.f};
#pragma unroll
        for (int kb = 0; kb < 4; ++kb) acc = MFMA16(wa[kb], af[nt][kb], acc);
        const int n = nt * 16 + l16;
        if (n < 49) {
          float4 o4;
          o4.x = acc[0] + pb4.x; o4.y = acc[1] + pb4.y;
          o4.z = acc[2] + pb4.z; o4.w = acc[3] + pb4.w;
          *(float4*)(ob + n * 128 + eb * 16 + (grp << 2)) = o4;
        }
      }
    }
  }
}

extern "C" void kernel_launch(void* const* d_in, const int* in_sizes, int n_in,
                              void* d_out, int out_size, void* d_ws, size_t ws_size,
                              hipStream_t stream) {
  const float* x      = (const float*)d_in[0];
  const float* qkv_w  = (const float*)d_in[1];
  const float* qkv_b  = (const float*)d_in[2];
  const float* proj_w = (const float*)d_in[3];
  const float* proj_b = (const float*)d_in[4];
  const float* rpb    = (const float*)d_in[5];
  const float* maskp  = (const float*)d_in[6];
  const int*   rel    = (const int*)d_in[7];

  bf16* wq     = (bf16*)d_ws;                          // 49152 bf16   @ 0
  bf16* wp     = (bf16*)((char*)d_ws + 98304);         // 16384 bf16
  float* biasp = (float*)((char*)d_ws + 131072);       // [4][64][64] f32
  bf16* maskb  = (bf16*)((char*)d_ws + 196608);        // [1024][64][64] bf16 (8.4 MB)

  prep_kernel<<<16704, 256, 0, stream>>>(qkv_w, proj_w, rpb, rel, maskp,
                                         wq, wp, biasp, maskb);
  swin_kernel<<<8192, 256, 0, stream>>>(x, qkv_b, proj_b, wq, wp, biasp, maskb,
                                        (float*)d_out);
}